// Round 1
// baseline (666.950 us; speedup 1.0000x reference)
//
#include <hip/hip_runtime.h>
#include <hip/hip_bf16.h>
#include <cstdint>
#include <cstddef>

#define BB 2
#define SS 2048
#define DD 1024
#define HH 16
#define EE 64

typedef short bf16x8 __attribute__((ext_vector_type(8)));
typedef float f32x4 __attribute__((ext_vector_type(4)));
typedef float float4v __attribute__((ext_vector_type(4)));

static __device__ __forceinline__ short f2bf(float f) {
    union { float f; uint32_t u; } v; v.f = f;
    uint32_t r = (v.u + 0x7fffu + ((v.u >> 16) & 1u)) >> 16;
    return (short)r;
}

// ---------------- fp32 -> bf16 convert (vectorized) ----------------
__global__ void convert_x_kernel(const float* __restrict__ x, short* __restrict__ xb, int n4) {
    int i = blockIdx.x * blockDim.x + threadIdx.x;
    if (i >= n4) return;
    float4v v = ((const float4v*)x)[i];
    short o0 = f2bf(v[0]), o1 = f2bf(v[1]), o2 = f2bf(v[2]), o3 = f2bf(v[3]);
    typedef short s4 __attribute__((ext_vector_type(4)));
    s4 o; o[0] = o0; o[1] = o1; o[2] = o2; o[3] = o3;
    ((s4*)xb)[i] = o;
}

// ------------- weight transpose+convert: [R x 64] -> [64 x R] bf16 -------------
// grid.x = R/64, grid.y = matrix index
__global__ void transpose_w_kernel(const float* __restrict__ src, short* __restrict__ dst, int R) {
    __shared__ float tile[64][65];
    int mtx = blockIdx.y;
    int r0 = blockIdx.x * 64;
    const float* s = src + (size_t)mtx * R * 64;
    short* d = dst + (size_t)mtx * R * 64;
    int t = threadIdx.x;
#pragma unroll
    for (int i = 0; i < 16; ++i) {
        int idx = t + i * 256;
        int r = idx >> 6, c = idx & 63;
        tile[r][c] = s[(size_t)(r0 + r) * 64 + c];
    }
    __syncthreads();
#pragma unroll
    for (int i = 0; i < 16; ++i) {
        int idx = t + i * 256;
        int e = idx >> 6, dd2 = idx & 63;
        d[(size_t)e * R + r0 + dd2] = f2bf(tile[dd2][e]);
    }
}

// ------------- per-head projection GEMM: X[b] (SxD) @ W[h] (DxE) -> [B,H,S,E] bf16 -------------
// wt layout: [H][E][D] (transposed) so B-fragments are contiguous.
// grid: x = S/64, y = B*H ; block 256 (4 waves, 16 rows each)
__global__ __launch_bounds__(256) void proj_kernel(const short* __restrict__ xb,
                                                   const short* __restrict__ wt,
                                                   short* __restrict__ out, float scale) {
    int wv = threadIdx.x >> 6, lane = threadIdx.x & 63;
    int m = lane & 15, g = lane >> 4;
    int bh = blockIdx.y; int b = bh >> 4, h = bh & 15;
    int srow = blockIdx.x * 64 + wv * 16;
    const short* arow = xb + ((size_t)(b * SS + srow + m)) * DD + g * 8;
    const short* wb = wt + (size_t)h * EE * DD + g * 8;
    f32x4 acc[4] = {{0,0,0,0},{0,0,0,0},{0,0,0,0},{0,0,0,0}};
    for (int d0 = 0; d0 < DD; d0 += 32) {
        bf16x8 a = *(const bf16x8*)(arow + d0);
#pragma unroll
        for (int n = 0; n < 4; ++n) {
            bf16x8 bbf = *(const bf16x8*)(wb + (size_t)(n * 16 + m) * DD + d0);
            acc[n] = __builtin_amdgcn_mfma_f32_16x16x32_bf16(a, bbf, acc[n], 0, 0, 0);
        }
    }
    short* orow = out + ((size_t)((b * HH + h) * SS + srow)) * EE;
#pragma unroll
    for (int n = 0; n < 4; ++n)
#pragma unroll
        for (int r = 0; r < 4; ++r)
            orow[(size_t)(g * 4 + r) * EE + n * 16 + m] = f2bf(acc[n][r] * scale);
}

// ------------- flash attention (causal) -------------
// grid: x = S/64 (q tiles), y = B*H ; block 256 (4 waves, 16 q-rows each)
__global__ __launch_bounds__(256) void attn_kernel(const short* __restrict__ Q,
                                                   const short* __restrict__ K,
                                                   const short* __restrict__ V,
                                                   short* __restrict__ ctx) {
    __shared__ short vt[64][72];        // V^T tile: [e][t], padded
    __shared__ short pl[4][16][72];     // per-wave P tile: [q][t], padded
    int wv = threadIdx.x >> 6, lane = threadIdx.x & 63;
    int m = lane & 15, g = lane >> 4;
    int bh = blockIdx.y; int b = bh >> 4, h = bh & 15;
    int q0 = blockIdx.x * 64;
    const short* Qb = Q + (size_t)bh * SS * EE;
    const short* Kb = K + (size_t)bh * SS * EE;
    const short* Vb = V + (size_t)bh * SS * EE;

    int qrow = q0 + wv * 16 + m;
    bf16x8 qa0 = *(const bf16x8*)(Qb + (size_t)qrow * EE + g * 8);
    bf16x8 qa1 = *(const bf16x8*)(Qb + (size_t)qrow * EE + 32 + g * 8);

    float mreg[4], lreg[4];
    f32x4 o[4];
#pragma unroll
    for (int r = 0; r < 4; ++r) { mreg[r] = -INFINITY; lreg[r] = 0.f; }
#pragma unroll
    for (int n = 0; n < 4; ++n) { o[n][0] = 0.f; o[n][1] = 0.f; o[n][2] = 0.f; o[n][3] = 0.f; }

    int ntile = blockIdx.x + 1;
    for (int tt = 0; tt < ntile; ++tt) {
        int t0 = tt * 64;
        __syncthreads();
        // stage V tile transposed into LDS
#pragma unroll
        for (int i = 0; i < 16; ++i) {
            int idx = i * 256 + threadIdx.x;
            int tr = idx >> 6, e = idx & 63;
            vt[e][tr] = Vb[(size_t)(t0 + tr) * EE + e];
        }
        __syncthreads();

        // QK^T: scores 16q x 64t per wave
        f32x4 s[4] = {{0,0,0,0},{0,0,0,0},{0,0,0,0},{0,0,0,0}};
#pragma unroll
        for (int n = 0; n < 4; ++n) {
            bf16x8 kb0 = *(const bf16x8*)(Kb + (size_t)(t0 + n * 16 + m) * EE + g * 8);
            s[n] = __builtin_amdgcn_mfma_f32_16x16x32_bf16(qa0, kb0, s[n], 0, 0, 0);
            bf16x8 kb1 = *(const bf16x8*)(Kb + (size_t)(t0 + n * 16 + m) * EE + 32 + g * 8);
            s[n] = __builtin_amdgcn_mfma_f32_16x16x32_bf16(qa1, kb1, s[n], 0, 0, 0);
        }

        // causal mask on diagonal tile
        if (t0 == q0) {
#pragma unroll
            for (int n = 0; n < 4; ++n)
#pragma unroll
                for (int r = 0; r < 4; ++r) {
                    int t = t0 + n * 16 + m;
                    int q = q0 + wv * 16 + g * 4 + r;
                    if (t > q) s[n][r] = -INFINITY;
                }
        }

        // online softmax (rows live across 16-lane groups)
#pragma unroll
        for (int r = 0; r < 4; ++r) {
            float mx = fmaxf(fmaxf(s[0][r], s[1][r]), fmaxf(s[2][r], s[3][r]));
#pragma unroll
            for (int off = 1; off < 16; off <<= 1) mx = fmaxf(mx, __shfl_xor(mx, off, 64));
            float mn = fmaxf(mreg[r], mx);
            float al = __expf(mreg[r] - mn);
            float sum = 0.f;
#pragma unroll
            for (int n = 0; n < 4; ++n) { float p = __expf(s[n][r] - mn); s[n][r] = p; sum += p; }
#pragma unroll
            for (int off = 1; off < 16; off <<= 1) sum += __shfl_xor(sum, off, 64);
            lreg[r] = lreg[r] * al + sum;
            mreg[r] = mn;
#pragma unroll
            for (int n = 0; n < 4; ++n) o[n][r] *= al;
        }

        // P -> LDS (bf16), per-wave private region
#pragma unroll
        for (int r = 0; r < 4; ++r)
#pragma unroll
            for (int n = 0; n < 4; ++n)
                pl[wv][g * 4 + r][n * 16 + m] = f2bf(s[n][r]);

        // PV: P (16q x 64t) @ V (64t x 64e)
#pragma unroll
        for (int ks = 0; ks < 2; ++ks) {
            bf16x8 pa = *(const bf16x8*)(&pl[wv][m][ks * 32 + g * 8]);
#pragma unroll
            for (int n = 0; n < 4; ++n) {
                bf16x8 vb = *(const bf16x8*)(&vt[n * 16 + m][ks * 32 + g * 8]);
                o[n] = __builtin_amdgcn_mfma_f32_16x16x32_bf16(pa, vb, o[n], 0, 0, 0);
            }
        }
    }

    // epilogue: normalize and write ctx [B,S,H*E] bf16
    short* cb = ctx + (size_t)(b * SS + q0 + wv * 16) * (HH * EE) + h * EE;
#pragma unroll
    for (int r = 0; r < 4; ++r) {
        float inv = 1.0f / lreg[r];
#pragma unroll
        for (int n = 0; n < 4; ++n)
            cb[(size_t)(g * 4 + r) * (HH * EE) + n * 16 + m] = f2bf(o[n][r] * inv);
    }
}

// ------------- output projection: ctx [4096,1024] @ W [1024,64] -> out fp32 -------------
// wot layout: [64][1024] (transposed). grid.x = 4096/64
__global__ __launch_bounds__(256) void outproj_kernel(const short* __restrict__ ctx,
                                                      const short* __restrict__ wot,
                                                      float* __restrict__ out) {
    int wv = threadIdx.x >> 6, lane = threadIdx.x & 63;
    int m = lane & 15, g = lane >> 4;
    int r0 = blockIdx.x * 64 + wv * 16;
    const short* arow = ctx + (size_t)(r0 + m) * (HH * EE) + g * 8;
    const short* wb = wot + g * 8;
    f32x4 acc[4] = {{0,0,0,0},{0,0,0,0},{0,0,0,0},{0,0,0,0}};
    for (int d0 = 0; d0 < HH * EE; d0 += 32) {
        bf16x8 a = *(const bf16x8*)(arow + d0);
#pragma unroll
        for (int n = 0; n < 4; ++n) {
            bf16x8 bbf = *(const bf16x8*)(wb + (size_t)(n * 16 + m) * (HH * EE) + d0);
            acc[n] = __builtin_amdgcn_mfma_f32_16x16x32_bf16(a, bbf, acc[n], 0, 0, 0);
        }
    }
    float* orow = out + (size_t)r0 * EE;
#pragma unroll
    for (int n = 0; n < 4; ++n)
#pragma unroll
        for (int r = 0; r < 4; ++r)
            orow[(size_t)(g * 4 + r) * EE + n * 16 + m] = acc[n][r];
}

extern "C" void kernel_launch(void* const* d_in, const int* in_sizes, int n_in,
                              void* d_out, int out_size, void* d_ws, size_t ws_size,
                              hipStream_t stream) {
    const float* x  = (const float*)d_in[0];
    const float* Wq = (const float*)d_in[1];
    const float* Wk = (const float*)d_in[2];
    const float* Wv = (const float*)d_in[3];
    const float* W  = (const float*)d_in[4];
    float* out = (float*)d_out;

    char* w = (char*)d_ws;
    short* xb  = (short*)w;                                   // 8 MB
    short* wqt = (short*)(w + ((size_t)8 << 20));             // 2 MB each
    short* wkt = wqt + (size_t)HH * EE * DD;
    short* wvt = wkt + (size_t)HH * EE * DD;
    short* wot = wvt + (size_t)HH * EE * DD;                  // 128 KB
    short* Qb  = wot + (size_t)64 * 1024;                     // 8 MB each
    short* Kb  = Qb + (size_t)BB * HH * SS * EE;
    short* Vb  = Kb + (size_t)BB * HH * SS * EE;
    short* ctx = Vb + (size_t)BB * HH * SS * EE;              // 8 MB

    int n4 = BB * SS * DD / 4;
    convert_x_kernel<<<n4 / 256, 256, 0, stream>>>(x, xb, n4);
    transpose_w_kernel<<<dim3(16, 16), 256, 0, stream>>>(Wq, wqt, DD);
    transpose_w_kernel<<<dim3(16, 16), 256, 0, stream>>>(Wk, wkt, DD);
    transpose_w_kernel<<<dim3(16, 16), 256, 0, stream>>>(Wv, wvt, DD);
    transpose_w_kernel<<<dim3(16, 1), 256, 0, stream>>>(W, wot, HH * EE);

    proj_kernel<<<dim3(32, 32), 256, 0, stream>>>(xb, wqt, Qb, 0.125f);
    proj_kernel<<<dim3(32, 32), 256, 0, stream>>>(xb, wkt, Kb, 1.0f);
    proj_kernel<<<dim3(32, 32), 256, 0, stream>>>(xb, wvt, Vb, 1.0f);

    attn_kernel<<<dim3(32, 32), 256, 0, stream>>>(Qb, Kb, Vb, ctx);
    outproj_kernel<<<64, 256, 0, stream>>>(ctx, wot, out);
}

// Round 2
// 377.465 us; speedup vs baseline: 1.7669x; 1.7669x over previous
//
#include <hip/hip_runtime.h>
#include <hip/hip_bf16.h>
#include <cstdint>
#include <cstddef>

#define BB 2
#define SS 2048
#define DD 1024
#define HH 16
#define EE 64

typedef short bf16x8 __attribute__((ext_vector_type(8)));
typedef short s4 __attribute__((ext_vector_type(4)));
typedef float f32x4 __attribute__((ext_vector_type(4)));
typedef float float4v __attribute__((ext_vector_type(4)));

static __device__ __forceinline__ short f2bf(float f) {
    union { float f; uint32_t u; } v; v.f = f;
    uint32_t r = (v.u + 0x7fffu + ((v.u >> 16) & 1u)) >> 16;
    return (short)r;
}

// ---------------- fp32 -> bf16 convert (vectorized) ----------------
__global__ void convert_x_kernel(const float* __restrict__ x, short* __restrict__ xb, int n4) {
    int i = blockIdx.x * blockDim.x + threadIdx.x;
    if (i >= n4) return;
    float4v v = ((const float4v*)x)[i];
    s4 o; o[0] = f2bf(v[0]); o[1] = f2bf(v[1]); o[2] = f2bf(v[2]); o[3] = f2bf(v[3]);
    ((s4*)xb)[i] = o;
}

// ------------- weight transpose+convert: [R x 64] -> [64 x R] bf16 -------------
__global__ void transpose_w_kernel(const float* __restrict__ src, short* __restrict__ dst, int R) {
    __shared__ float tile[64][65];
    int mtx = blockIdx.y;
    int r0 = blockIdx.x * 64;
    const float* s = src + (size_t)mtx * R * 64;
    short* d = dst + (size_t)mtx * R * 64;
    int t = threadIdx.x;
#pragma unroll
    for (int i = 0; i < 16; ++i) {
        int idx = t + i * 256;
        int r = idx >> 6, c = idx & 63;
        tile[r][c] = s[(size_t)(r0 + r) * 64 + c];
    }
    __syncthreads();
#pragma unroll
    for (int i = 0; i < 16; ++i) {
        int idx = t + i * 256;
        int e = idx >> 6, dd2 = idx & 63;
        d[(size_t)e * R + r0 + dd2] = f2bf(tile[dd2][e]);
    }
}

// ------------- fused QKV projection -------------
// X[b] (SxD) @ {Wq,Wk,Wv}[h] (DxE). Weights pre-transposed [H][E][D].
// Q,K written [B*H][S][E] row-major (Q pre-scaled by 1/8); V written transposed [B*H][E][S].
// grid: x = S/64, y = B*H ; block 256 (4 waves, 16 rows each)
__global__ __launch_bounds__(256) void qkv_kernel(const short* __restrict__ xb,
                                                  const short* __restrict__ wqt,
                                                  const short* __restrict__ wkt,
                                                  const short* __restrict__ wvt,
                                                  short* __restrict__ Qo,
                                                  short* __restrict__ Ko,
                                                  short* __restrict__ Vto) {
    int wv = threadIdx.x >> 6, lane = threadIdx.x & 63;
    int m = lane & 15, g = lane >> 4;
    int bh = blockIdx.y; int b = bh >> 4, h = bh & 15;
    int srow = blockIdx.x * 64 + wv * 16;
    const short* arow = xb + ((size_t)(b * SS + srow + m)) * DD + g * 8;
    const short* wq = wqt + (size_t)h * EE * DD + g * 8;
    const short* wk = wkt + (size_t)h * EE * DD + g * 8;
    const short* wvp = wvt + (size_t)h * EE * DD + g * 8;
    f32x4 aq[4], ak[4], av[4];
#pragma unroll
    for (int n = 0; n < 4; ++n) { aq[n] = {0,0,0,0}; ak[n] = {0,0,0,0}; av[n] = {0,0,0,0}; }
    for (int d0 = 0; d0 < DD; d0 += 32) {
        bf16x8 a = *(const bf16x8*)(arow + d0);
#pragma unroll
        for (int n = 0; n < 4; ++n) {
            size_t roff = (size_t)(n * 16 + m) * DD + d0;
            bf16x8 bq = *(const bf16x8*)(wq + roff);
            bf16x8 bk = *(const bf16x8*)(wk + roff);
            bf16x8 bv = *(const bf16x8*)(wvp + roff);
            aq[n] = __builtin_amdgcn_mfma_f32_16x16x32_bf16(a, bq, aq[n], 0, 0, 0);
            ak[n] = __builtin_amdgcn_mfma_f32_16x16x32_bf16(a, bk, ak[n], 0, 0, 0);
            av[n] = __builtin_amdgcn_mfma_f32_16x16x32_bf16(a, bv, av[n], 0, 0, 0);
        }
    }
    short* qrow = Qo + ((size_t)(bh * SS + srow)) * EE;
    short* krow = Ko + ((size_t)(bh * SS + srow)) * EE;
#pragma unroll
    for (int n = 0; n < 4; ++n)
#pragma unroll
        for (int r = 0; r < 4; ++r) {
            qrow[(size_t)(g * 4 + r) * EE + n * 16 + m] = f2bf(aq[n][r] * 0.125f);
            krow[(size_t)(g * 4 + r) * EE + n * 16 + m] = f2bf(ak[n][r]);
        }
    // V transposed: Vto[bh][e][t], e = n*16+m, t = srow + g*4 + r  (short4 store)
    short* vbase = Vto + (size_t)bh * EE * SS;
#pragma unroll
    for (int n = 0; n < 4; ++n) {
        s4 o; o[0] = f2bf(av[n][0]); o[1] = f2bf(av[n][1]); o[2] = f2bf(av[n][2]); o[3] = f2bf(av[n][3]);
        *(s4*)(vbase + (size_t)(n * 16 + m) * SS + srow + g * 4) = o;
    }
}

// ------------- flash attention (causal), barrier-free -------------
// One wave owns one 16-row Q group. 4096 waves total, heavy groups first.
// K read row-major from global; V read from pre-transposed Vt; P via wave-private LDS.
__global__ __launch_bounds__(256) void attn_kernel(const short* __restrict__ Q,
                                                   const short* __restrict__ K,
                                                   const short* __restrict__ Vt,
                                                   short* __restrict__ ctx) {
    __shared__ short pl[4][16][76];     // per-wave P tile [q][t], 76-pad (write conflict-free)
    int wv = threadIdx.x >> 6, lane = threadIdx.x & 63;
    int m = lane & 15, g = lane >> 4;
    int W = blockIdx.x * 4 + wv;        // 0..4095
    int qg = 127 - (W >> 5);            // q group 0..127, heaviest first
    int bh = W & 31;
    int b = bh >> 4, h = bh & 15;
    const short* Qb = Q + (size_t)bh * SS * EE;
    const short* Kb = K + (size_t)bh * SS * EE;
    const short* Vb = Vt + (size_t)bh * EE * SS;
    int q0 = qg * 16;

    bf16x8 qa0 = *(const bf16x8*)(Qb + (size_t)(q0 + m) * EE + g * 8);
    bf16x8 qa1 = *(const bf16x8*)(Qb + (size_t)(q0 + m) * EE + 32 + g * 8);

    float mreg[4], lreg[4];
    f32x4 o[4];
#pragma unroll
    for (int r = 0; r < 4; ++r) { mreg[r] = -INFINITY; lreg[r] = 0.f; }
#pragma unroll
    for (int n = 0; n < 4; ++n) { o[n][0] = 0.f; o[n][1] = 0.f; o[n][2] = 0.f; o[n][3] = 0.f; }

    int dtile = qg >> 2;
    int ntile = dtile + 1;
    for (int tt = 0; tt < ntile; ++tt) {
        int t0 = tt * 64;

        // QK^T: 16q x 64t
        f32x4 s[4] = {{0,0,0,0},{0,0,0,0},{0,0,0,0},{0,0,0,0}};
#pragma unroll
        for (int n = 0; n < 4; ++n) {
            bf16x8 kb0 = *(const bf16x8*)(Kb + (size_t)(t0 + n * 16 + m) * EE + g * 8);
            s[n] = __builtin_amdgcn_mfma_f32_16x16x32_bf16(qa0, kb0, s[n], 0, 0, 0);
            bf16x8 kb1 = *(const bf16x8*)(Kb + (size_t)(t0 + n * 16 + m) * EE + 32 + g * 8);
            s[n] = __builtin_amdgcn_mfma_f32_16x16x32_bf16(qa1, kb1, s[n], 0, 0, 0);
        }

        if (tt == dtile) {
#pragma unroll
            for (int n = 0; n < 4; ++n)
#pragma unroll
                for (int r = 0; r < 4; ++r) {
                    int t = t0 + n * 16 + m;
                    int q = q0 + g * 4 + r;
                    if (t > q) s[n][r] = -INFINITY;
                }
        }

        // online softmax (rows live across the 16 m-lanes)
#pragma unroll
        for (int r = 0; r < 4; ++r) {
            float mx = fmaxf(fmaxf(s[0][r], s[1][r]), fmaxf(s[2][r], s[3][r]));
#pragma unroll
            for (int off = 1; off < 16; off <<= 1) mx = fmaxf(mx, __shfl_xor(mx, off, 64));
            float mn = fmaxf(mreg[r], mx);
            float al = __expf(mreg[r] - mn);
            float sum = 0.f;
#pragma unroll
            for (int n = 0; n < 4; ++n) { float p = __expf(s[n][r] - mn); s[n][r] = p; sum += p; }
#pragma unroll
            for (int off = 1; off < 16; off <<= 1) sum += __shfl_xor(sum, off, 64);
            lreg[r] = lreg[r] * al + sum;
            mreg[r] = mn;
#pragma unroll
            for (int n = 0; n < 4; ++n) o[n][r] *= al;
        }

        // P -> wave-private LDS (no barrier needed; in-wave lgkmcnt ordering)
#pragma unroll
        for (int r = 0; r < 4; ++r)
#pragma unroll
            for (int n = 0; n < 4; ++n)
                pl[wv][g * 4 + r][n * 16 + m] = f2bf(s[n][r]);

        // PV: P (16q x 64t) @ V (64t x 64e), V fragments straight from Vt
#pragma unroll
        for (int ks = 0; ks < 2; ++ks) {
            bf16x8 pa = *(const bf16x8*)(&pl[wv][m][ks * 32 + g * 8]);
#pragma unroll
            for (int n = 0; n < 4; ++n) {
                bf16x8 vb = *(const bf16x8*)(Vb + (size_t)(n * 16 + m) * SS + t0 + ks * 32 + g * 8);
                o[n] = __builtin_amdgcn_mfma_f32_16x16x32_bf16(pa, vb, o[n], 0, 0, 0);
            }
        }
    }

    // epilogue: normalize, write ctx [B,S,H*E] bf16
#pragma unroll
    for (int r = 0; r < 4; ++r) {
        float inv = 1.0f / lreg[r];
#pragma unroll
        for (int n = 0; n < 4; ++n)
            ctx[(size_t)(b * SS + q0 + g * 4 + r) * (HH * EE) + h * EE + n * 16 + m] = f2bf(o[n][r] * inv);
    }
}

// ------------- output projection: ctx [4096,1024] @ W [1024,64] -> out fp32 -------------
__global__ __launch_bounds__(256) void outproj_kernel(const short* __restrict__ ctx,
                                                      const short* __restrict__ wot,
                                                      float* __restrict__ out) {
    int wv = threadIdx.x >> 6, lane = threadIdx.x & 63;
    int m = lane & 15, g = lane >> 4;
    int r0 = blockIdx.x * 64 + wv * 16;
    const short* arow = ctx + (size_t)(r0 + m) * (HH * EE) + g * 8;
    const short* wb = wot + g * 8;
    f32x4 acc[4] = {{0,0,0,0},{0,0,0,0},{0,0,0,0},{0,0,0,0}};
    for (int d0 = 0; d0 < HH * EE; d0 += 32) {
        bf16x8 a = *(const bf16x8*)(arow + d0);
#pragma unroll
        for (int n = 0; n < 4; ++n) {
            bf16x8 bbf = *(const bf16x8*)(wb + (size_t)(n * 16 + m) * (HH * EE) + d0);
            acc[n] = __builtin_amdgcn_mfma_f32_16x16x32_bf16(a, bbf, acc[n], 0, 0, 0);
        }
    }
    float* orow = out + (size_t)r0 * EE;
#pragma unroll
    for (int n = 0; n < 4; ++n)
#pragma unroll
        for (int r = 0; r < 4; ++r)
            orow[(size_t)(g * 4 + r) * EE + n * 16 + m] = acc[n][r];
}

extern "C" void kernel_launch(void* const* d_in, const int* in_sizes, int n_in,
                              void* d_out, int out_size, void* d_ws, size_t ws_size,
                              hipStream_t stream) {
    const float* x  = (const float*)d_in[0];
    const float* Wq = (const float*)d_in[1];
    const float* Wk = (const float*)d_in[2];
    const float* Wv = (const float*)d_in[3];
    const float* W  = (const float*)d_in[4];
    float* out = (float*)d_out;

    char* w = (char*)d_ws;
    short* xb  = (short*)w;                                   // 8 MB
    short* wqt = (short*)(w + ((size_t)8 << 20));             // 2 MB each
    short* wkt = wqt + (size_t)HH * EE * DD;
    short* wvt = wkt + (size_t)HH * EE * DD;
    short* wot = wvt + (size_t)HH * EE * DD;                  // 128 KB
    short* Qb  = wot + (size_t)64 * 1024;                     // 8 MB each
    short* Kb  = Qb + (size_t)BB * HH * SS * EE;
    short* Vtb = Kb + (size_t)BB * HH * SS * EE;
    short* ctx = Vtb + (size_t)BB * HH * SS * EE;             // 8 MB

    int n4 = BB * SS * DD / 4;
    convert_x_kernel<<<n4 / 256, 256, 0, stream>>>(x, xb, n4);
    transpose_w_kernel<<<dim3(16, 16), 256, 0, stream>>>(Wq, wqt, DD);
    transpose_w_kernel<<<dim3(16, 16), 256, 0, stream>>>(Wk, wkt, DD);
    transpose_w_kernel<<<dim3(16, 16), 256, 0, stream>>>(Wv, wvt, DD);
    transpose_w_kernel<<<dim3(16, 1), 256, 0, stream>>>(W, wot, HH * EE);

    qkv_kernel<<<dim3(32, 32), 256, 0, stream>>>(xb, wqt, wkt, wvt, Qb, Kb, Vtb);
    attn_kernel<<<1024, 256, 0, stream>>>(Qb, Kb, Vtb, ctx);
    outproj_kernel<<<64, 256, 0, stream>>>(ctx, wot, out);
}

// Round 3
// 230.678 us; speedup vs baseline: 2.8913x; 1.6363x over previous
//
#include <hip/hip_runtime.h>
#include <hip/hip_bf16.h>
#include <cstdint>
#include <cstddef>

#define BB 2
#define SS 2048
#define DD 1024
#define HH 16
#define EE 64

typedef short bf16x8 __attribute__((ext_vector_type(8)));
typedef short s4 __attribute__((ext_vector_type(4)));
typedef float f32x4 __attribute__((ext_vector_type(4)));
typedef float float4v __attribute__((ext_vector_type(4)));

#define GLDS(gp, lp) __builtin_amdgcn_global_load_lds( \
    (const __attribute__((address_space(1))) void*)(gp), \
    (__attribute__((address_space(3))) void*)(lp), 16, 0, 0)

static __device__ __forceinline__ short f2bf(float f) {
    union { float f; uint32_t u; } v; v.f = f;
    uint32_t r = (v.u + 0x7fffu + ((v.u >> 16) & 1u)) >> 16;
    return (short)r;
}

// ---------------- fp32 -> bf16 convert (vectorized) ----------------
__global__ void convert_x_kernel(const float* __restrict__ x, short* __restrict__ xb, int n4) {
    int i = blockIdx.x * blockDim.x + threadIdx.x;
    if (i >= n4) return;
    float4v v = ((const float4v*)x)[i];
    s4 o; o[0] = f2bf(v[0]); o[1] = f2bf(v[1]); o[2] = f2bf(v[2]); o[3] = f2bf(v[3]);
    ((s4*)xb)[i] = o;
}

// ------------- weight transpose+convert: [R x 64] -> [64 x R] bf16 -------------
__global__ void transpose_w_kernel(const float* __restrict__ src, short* __restrict__ dst, int R) {
    __shared__ float tile[64][65];
    int mtx = blockIdx.y;
    int r0 = blockIdx.x * 64;
    const float* s = src + (size_t)mtx * R * 64;
    short* d = dst + (size_t)mtx * R * 64;
    int t = threadIdx.x;
#pragma unroll
    for (int i = 0; i < 16; ++i) {
        int idx = t + i * 256;
        int r = idx >> 6, c = idx & 63;
        tile[r][c] = s[(size_t)(r0 + r) * 64 + c];
    }
    __syncthreads();
#pragma unroll
    for (int i = 0; i < 16; ++i) {
        int idx = t + i * 256;
        int e = idx >> 6, dd2 = idx & 63;
        d[(size_t)e * R + r0 + dd2] = f2bf(tile[dd2][e]);
    }
}

// ------------- QKV as one m97-style GEMM -------------
// C = X[4096,1024] @ Bt[3072,1024]^T, Bt = [wq^T | wk^T | wv^T] (contiguous).
// 128x128 tile, BK=32, 4 waves (2x2), 4x4 16x16 fragments per wave.
// Epilogue scatters: mtx0 -> Q (scaled 1/8, row-major [BH][S][E]),
// mtx1 -> K (row-major), mtx2 -> V transposed ([BH][E][S]).
__global__ __launch_bounds__(256) void qkv_gemm(const short* __restrict__ A,
                                                const short* __restrict__ Bt,
                                                short* __restrict__ Qo,
                                                short* __restrict__ Ko,
                                                short* __restrict__ Vto) {
    __shared__ short As[128 * 32];
    __shared__ short Bs[128 * 32];
    int tid = threadIdx.x;
    int wv = tid >> 6, lane = tid & 63;
    int m = lane & 15, g = lane >> 4;
    int wr = wv >> 1, wc = wv & 1;

    // XCD-bijective swizzle (768 % 8 == 0)
    int wg = (blockIdx.x & 7) * 96 + (blockIdx.x >> 3);
    int mb = wg / 24, nb = wg % 24;
    int rowBase = mb * 128, colBase0 = nb * 128;

    // staging source: issue j covers tile rows [j*64+wv*16, +16)
    int strow = wv * 16 + (lane >> 2);
    int stcol = (lane & 3) * 8;
    const short* a0 = A + (size_t)(rowBase + strow) * DD + stcol;
    const short* b0 = Bt + (size_t)(colBase0 + strow) * DD + stcol;
    short* AsW0 = As + wv * 512;          // issue 0 dest (1KB/wave)
    short* AsW1 = As + (4 + wv) * 512;    // issue 1 dest
    short* BsW0 = Bs + wv * 512;
    short* BsW1 = Bs + (4 + wv) * 512;

    f32x4 acc[4][4];
#pragma unroll
    for (int i = 0; i < 4; ++i)
#pragma unroll
        for (int j = 0; j < 4; ++j) acc[i][j] = {0, 0, 0, 0};

    for (int kt = 0; kt < DD; kt += 32) {
        __syncthreads();
        GLDS(a0 + kt, AsW0);
        GLDS(a0 + kt + (size_t)64 * DD, AsW1);
        GLDS(b0 + kt, BsW0);
        GLDS(b0 + kt + (size_t)64 * DD, BsW1);
        __syncthreads();

        bf16x8 af[4], bfr[4];
#pragma unroll
        for (int mi = 0; mi < 4; ++mi)
            af[mi] = *(const bf16x8*)&As[(wr * 64 + mi * 16 + m) * 32 + g * 8];
#pragma unroll
        for (int ni = 0; ni < 4; ++ni)
            bfr[ni] = *(const bf16x8*)&Bs[(wc * 64 + ni * 16 + m) * 32 + g * 8];
#pragma unroll
        for (int mi = 0; mi < 4; ++mi)
#pragma unroll
            for (int ni = 0; ni < 4; ++ni)
                acc[mi][ni] = __builtin_amdgcn_mfma_f32_16x16x32_bf16(af[mi], bfr[ni], acc[mi][ni], 0, 0, 0);
    }

    // epilogue scatter
    int colBase = colBase0 + wc * 64;          // multiple of 64
    int mtx = colBase >> 10;                   // 0=Q 1=K 2=V (wave-uniform)
    int h = (colBase >> 6) & 15;
    int rb = rowBase + wr * 64;

    if (mtx == 0) {
#pragma unroll
        for (int mi = 0; mi < 4; ++mi)
#pragma unroll
            for (int ni = 0; ni < 4; ++ni)
#pragma unroll
                for (int r = 0; r < 4; ++r) {
                    int row = rb + mi * 16 + g * 4 + r;
                    int b = row >> 11, s = row & 2047;
                    Qo[((size_t)(b * HH + h) * SS + s) * EE + ni * 16 + m] = f2bf(acc[mi][ni][r] * 0.125f);
                }
    } else if (mtx == 1) {
#pragma unroll
        for (int mi = 0; mi < 4; ++mi)
#pragma unroll
            for (int ni = 0; ni < 4; ++ni)
#pragma unroll
                for (int r = 0; r < 4; ++r) {
                    int row = rb + mi * 16 + g * 4 + r;
                    int b = row >> 11, s = row & 2047;
                    Ko[((size_t)(b * HH + h) * SS + s) * EE + ni * 16 + m] = f2bf(acc[mi][ni][r]);
                }
    } else {
#pragma unroll
        for (int mi = 0; mi < 4; ++mi)
#pragma unroll
            for (int ni = 0; ni < 4; ++ni) {
                int row0 = rb + mi * 16 + g * 4;
                int b = row0 >> 11, s = row0 & 2047;
                s4 o; o[0] = f2bf(acc[mi][ni][0]); o[1] = f2bf(acc[mi][ni][1]);
                o[2] = f2bf(acc[mi][ni][2]); o[3] = f2bf(acc[mi][ni][3]);
                *(s4*)&Vto[((size_t)(b * HH + h) * EE + ni * 16 + m) * SS + s] = o;
            }
    }
}

// ------------- flash attention (causal), barrier-free -------------
__global__ __launch_bounds__(256) void attn_kernel(const short* __restrict__ Q,
                                                   const short* __restrict__ K,
                                                   const short* __restrict__ Vt,
                                                   short* __restrict__ ctx) {
    __shared__ short pl[4][16][76];
    int wv = threadIdx.x >> 6, lane = threadIdx.x & 63;
    int m = lane & 15, g = lane >> 4;
    int W = blockIdx.x * 4 + wv;
    int qg = 127 - (W >> 5);
    int bh = W & 31;
    int b = bh >> 4, h = bh & 15;
    const short* Qb = Q + (size_t)bh * SS * EE;
    const short* Kb = K + (size_t)bh * SS * EE;
    const short* Vb = Vt + (size_t)bh * EE * SS;
    int q0 = qg * 16;

    bf16x8 qa0 = *(const bf16x8*)(Qb + (size_t)(q0 + m) * EE + g * 8);
    bf16x8 qa1 = *(const bf16x8*)(Qb + (size_t)(q0 + m) * EE + 32 + g * 8);

    float mreg[4], lreg[4];
    f32x4 o[4];
#pragma unroll
    for (int r = 0; r < 4; ++r) { mreg[r] = -INFINITY; lreg[r] = 0.f; }
#pragma unroll
    for (int n = 0; n < 4; ++n) { o[n][0] = 0.f; o[n][1] = 0.f; o[n][2] = 0.f; o[n][3] = 0.f; }

    int dtile = qg >> 2;
    int ntile = dtile + 1;
    for (int tt = 0; tt < ntile; ++tt) {
        int t0 = tt * 64;

        f32x4 s[4] = {{0,0,0,0},{0,0,0,0},{0,0,0,0},{0,0,0,0}};
#pragma unroll
        for (int n = 0; n < 4; ++n) {
            bf16x8 kb0 = *(const bf16x8*)(Kb + (size_t)(t0 + n * 16 + m) * EE + g * 8);
            s[n] = __builtin_amdgcn_mfma_f32_16x16x32_bf16(qa0, kb0, s[n], 0, 0, 0);
            bf16x8 kb1 = *(const bf16x8*)(Kb + (size_t)(t0 + n * 16 + m) * EE + 32 + g * 8);
            s[n] = __builtin_amdgcn_mfma_f32_16x16x32_bf16(qa1, kb1, s[n], 0, 0, 0);
        }

        if (tt == dtile) {
#pragma unroll
            for (int n = 0; n < 4; ++n)
#pragma unroll
                for (int r = 0; r < 4; ++r) {
                    int t = t0 + n * 16 + m;
                    int q = q0 + g * 4 + r;
                    if (t > q) s[n][r] = -INFINITY;
                }
        }

#pragma unroll
        for (int r = 0; r < 4; ++r) {
            float mx = fmaxf(fmaxf(s[0][r], s[1][r]), fmaxf(s[2][r], s[3][r]));
#pragma unroll
            for (int off = 1; off < 16; off <<= 1) mx = fmaxf(mx, __shfl_xor(mx, off, 64));
            float mn = fmaxf(mreg[r], mx);
            float al = __expf(mreg[r] - mn);
            float sum = 0.f;
#pragma unroll
            for (int n = 0; n < 4; ++n) { float p = __expf(s[n][r] - mn); s[n][r] = p; sum += p; }
#pragma unroll
            for (int off = 1; off < 16; off <<= 1) sum += __shfl_xor(sum, off, 64);
            lreg[r] = lreg[r] * al + sum;
            mreg[r] = mn;
#pragma unroll
            for (int n = 0; n < 4; ++n) o[n][r] *= al;
        }

#pragma unroll
        for (int r = 0; r < 4; ++r)
#pragma unroll
            for (int n = 0; n < 4; ++n)
                pl[wv][g * 4 + r][n * 16 + m] = f2bf(s[n][r]);

#pragma unroll
        for (int ks = 0; ks < 2; ++ks) {
            bf16x8 pa = *(const bf16x8*)(&pl[wv][m][ks * 32 + g * 8]);
#pragma unroll
            for (int n = 0; n < 4; ++n) {
                bf16x8 vb = *(const bf16x8*)(Vb + (size_t)(n * 16 + m) * SS + t0 + ks * 32 + g * 8);
                o[n] = __builtin_amdgcn_mfma_f32_16x16x32_bf16(pa, vb, o[n], 0, 0, 0);
            }
        }
    }

#pragma unroll
    for (int r = 0; r < 4; ++r) {
        float inv = 1.0f / lreg[r];
#pragma unroll
        for (int n = 0; n < 4; ++n)
            ctx[(size_t)(b * SS + q0 + g * 4 + r) * (HH * EE) + h * EE + n * 16 + m] = f2bf(o[n][r] * inv);
    }
}

// ------------- output projection: ctx [4096,1024] @ W [1024,64] -> out fp32 -------------
__global__ __launch_bounds__(256) void outproj_kernel(const short* __restrict__ ctx,
                                                      const short* __restrict__ wot,
                                                      float* __restrict__ out) {
    int wv = threadIdx.x >> 6, lane = threadIdx.x & 63;
    int m = lane & 15, g = lane >> 4;
    int r0 = blockIdx.x * 64 + wv * 16;
    const short* arow = ctx + (size_t)(r0 + m) * (HH * EE) + g * 8;
    const short* wb = wot + g * 8;
    f32x4 acc[4] = {{0,0,0,0},{0,0,0,0},{0,0,0,0},{0,0,0,0}};
    for (int d0 = 0; d0 < HH * EE; d0 += 32) {
        bf16x8 a = *(const bf16x8*)(arow + d0);
#pragma unroll
        for (int n = 0; n < 4; ++n) {
            bf16x8 bbf = *(const bf16x8*)(wb + (size_t)(n * 16 + m) * (HH * EE) + d0);
            acc[n] = __builtin_amdgcn_mfma_f32_16x16x32_bf16(a, bbf, acc[n], 0, 0, 0);
        }
    }
    float* orow = out + (size_t)r0 * EE;
#pragma unroll
    for (int n = 0; n < 4; ++n)
#pragma unroll
        for (int r = 0; r < 4; ++r)
            orow[(size_t)(g * 4 + r) * EE + n * 16 + m] = acc[n][r];
}

extern "C" void kernel_launch(void* const* d_in, const int* in_sizes, int n_in,
                              void* d_out, int out_size, void* d_ws, size_t ws_size,
                              hipStream_t stream) {
    const float* x  = (const float*)d_in[0];
    const float* Wq = (const float*)d_in[1];
    const float* Wk = (const float*)d_in[2];
    const float* Wv = (const float*)d_in[3];
    const float* W  = (const float*)d_in[4];
    float* out = (float*)d_out;

    char* w = (char*)d_ws;
    short* xb  = (short*)w;                                   // 8 MB
    short* wqt = (short*)(w + ((size_t)8 << 20));             // 2 MB each, contiguous = Bt
    short* wkt = wqt + (size_t)HH * EE * DD;
    short* wvt = wkt + (size_t)HH * EE * DD;
    short* wot = wvt + (size_t)HH * EE * DD;                  // 128 KB
    short* Qb  = wot + (size_t)64 * 1024;                     // 8 MB each
    short* Kb  = Qb + (size_t)BB * HH * SS * EE;
    short* Vtb = Kb + (size_t)BB * HH * SS * EE;
    short* ctx = Vtb + (size_t)BB * HH * SS * EE;             // 8 MB

    int n4 = BB * SS * DD / 4;
    convert_x_kernel<<<n4 / 256, 256, 0, stream>>>(x, xb, n4);
    transpose_w_kernel<<<dim3(16, 16), 256, 0, stream>>>(Wq, wqt, DD);
    transpose_w_kernel<<<dim3(16, 16), 256, 0, stream>>>(Wk, wkt, DD);
    transpose_w_kernel<<<dim3(16, 16), 256, 0, stream>>>(Wv, wvt, DD);
    transpose_w_kernel<<<dim3(16, 1), 256, 0, stream>>>(W, wot, HH * EE);

    qkv_gemm<<<768, 256, 0, stream>>>(xb, wqt, Qb, Kb, Vtb);
    attn_kernel<<<1024, 256, 0, stream>>>(Qb, Kb, Vtb, ctx);
    outproj_kernel<<<64, 256, 0, stream>>>(ctx, wot, out);
}